// Round 2
// baseline (115.858 us; speedup 1.0000x reference)
//
#include <hip/hip_runtime.h>

#define TPB1 128          // frames kernel: one thread per residue
#define TPB2 256          // atoms kernel: one thread per output float
#define ASTRIDE 22        // padded alphas stride in LDS floats (2-way bank alias = free)

// ---------- small matrix helpers (all row-major) ----------

__device__ __forceinline__ void load16(float* M, const float* __restrict__ p) {
    const float4* q = reinterpret_cast<const float4*>(p);
    float4 v0 = q[0], v1 = q[1], v2 = q[2], v3 = q[3];
    M[0]=v0.x; M[1]=v0.y; M[2]=v0.z; M[3]=v0.w;
    M[4]=v1.x; M[5]=v1.y; M[6]=v1.z; M[7]=v1.w;
    M[8]=v2.x; M[9]=v2.y; M[10]=v2.z; M[11]=v2.w;
    M[12]=v3.x; M[13]=v3.y; M[14]=v3.z; M[15]=v3.w;
}

__device__ __forceinline__ void store16(float* __restrict__ p, const float* M) {
    float4* q = reinterpret_cast<float4*>(p);
    q[0] = make_float4(M[0],M[1],M[2],M[3]);
    q[1] = make_float4(M[4],M[5],M[6],M[7]);
    q[2] = make_float4(M[8],M[9],M[10],M[11]);
    q[3] = make_float4(M[12],M[13],M[14],M[15]);
}

// P(4x4) = [Ar | 0001] * B(4x4); Ar = rows 0..2 incl translation (12 floats)
__device__ __forceinline__ void mul_affine(float* __restrict__ P,
                                           const float* __restrict__ Ar,
                                           const float* __restrict__ B) {
#pragma unroll
    for (int i = 0; i < 3; ++i) {
#pragma unroll
        for (int j = 0; j < 4; ++j) {
            float t = Ar[i*4+0] * B[0*4+j];
            t = fmaf(Ar[i*4+1], B[1*4+j], t);
            t = fmaf(Ar[i*4+2], B[2*4+j], t);
            t = fmaf(Ar[i*4+3], B[3*4+j], t);
            P[i*4+j] = t;
        }
    }
#pragma unroll
    for (int j = 0; j < 4; ++j) P[12+j] = B[12+j];
}

__device__ __forceinline__ void mul_full(float* __restrict__ P,
                                         const float* __restrict__ A,
                                         const float* __restrict__ B) {
#pragma unroll
    for (int i = 0; i < 4; ++i) {
#pragma unroll
        for (int j = 0; j < 4; ++j) {
            float t = A[i*4+0] * B[0*4+j];
            t = fmaf(A[i*4+1], B[1*4+j], t);
            t = fmaf(A[i*4+2], B[2*4+j], t);
            t = fmaf(A[i*4+3], B[3*4+j], t);
            P[i*4+j] = t;
        }
    }
}

// M = M @ rotX(c,s): only columns 1,2 change
__device__ __forceinline__ void apply_rotX(float* M, float c, float s) {
#pragma unroll
    for (int i = 0; i < 4; ++i) {
        float t1 = M[i*4+1], t2 = M[i*4+2];
        M[i*4+1] = fmaf(t2, s, t1*c);
        M[i*4+2] = fmaf(t2, c, -(t1*s));
    }
}

// M = M @ rotZ(c,s): only columns 0,1 change
__device__ __forceinline__ void apply_rotZ(float* M, float c, float s) {
#pragma unroll
    for (int i = 0; i < 4; ++i) {
        float t0 = M[i*4+0], t1 = M[i*4+1];
        M[i*4+0] = fmaf(t1, s, t0*c);
        M[i*4+1] = fmaf(t1, c, -(t0*s));
    }
}

__device__ __forceinline__ void rot_axis3(float* R, float ct, float st,
                                          float u0, float u1, float u2) {
    float omc = 1.0f - ct;
    R[0] = ct + u0*u0*omc;       R[1] = u0*u1*omc - u2*st;   R[2] = u0*u2*omc + u1*st;
    R[3] = u0*u1*omc + u2*st;    R[4] = ct + u1*u1*omc;      R[5] = u1*u2*omc - u0*st;
    R[6] = u0*u2*omc - u1*st;    R[7] = u1*u2*omc + u0*st;   R[8] = ct + u2*u2*omc;
}

__device__ __forceinline__ void mul3_a4(float* C, const float* A, const float* B) {
#pragma unroll
    for (int i = 0; i < 3; ++i)
#pragma unroll
        for (int j = 0; j < 3; ++j) {
            float t = A[i*4+0] * B[0*3+j];
            t = fmaf(A[i*4+1], B[1*3+j], t);
            t = fmaf(A[i*4+2], B[2*3+j], t);
            C[i*3+j] = t;
        }
}

__device__ __forceinline__ void mul3(float* C, const float* A, const float* B) {
#pragma unroll
    for (int i = 0; i < 3; ++i)
#pragma unroll
        for (int j = 0; j < 3; ++j) {
            float t = A[i*3+0] * B[0*3+j];
            t = fmaf(A[i*3+1], B[1*3+j], t);
            t = fmaf(A[i*3+2], B[2*3+j], t);
            C[i*3+j] = t;
        }
}

// ---------- kernel 1: frames ----------

extern "C" __global__ void __launch_bounds__(TPB1)
frames_kernel(const float* __restrict__ xyz,     // (L,3,3)
              const float* __restrict__ alphas,  // (L,10,2)
              const float* __restrict__ RTs,     // (22,7,4,4)
              const float* __restrict__ bxyz,    // (22,27,4)
              const int*   __restrict__ seq,     // (L)
              float* __restrict__ outF,          // (L,9,4,4)
              int L)
{
    __shared__ float sX[TPB1 * 9];        // 4.6 KB
    __shared__ float sA[TPB1 * ASTRIDE];  // 11.3 KB

    const int tid  = threadIdx.x;
    const int base = blockIdx.x * TPB1;
    const int l    = base + tid;

    // ---- coalesced staging of xyz (9 floats/res) and alphas (20 floats/res) ----
    {
        // xyz: 1152 floats = 288 float4 per full block
        const float4* gx = reinterpret_cast<const float4*>(xyz + (size_t)base * 9);
        int nfl4 = ((min(TPB1, L - base)) * 9) >> 2;   // floor; handle tail floats below
        int nflt = min(TPB1, L - base) * 9;
        for (int j = tid; j < nfl4; j += TPB1)
            reinterpret_cast<float4*>(sX)[j] = gx[j];
        for (int j = (nfl4 << 2) + tid; j < nflt; j += TPB1)
            sX[j] = xyz[(size_t)base * 9 + j];

        // alphas: copy as float2 pairs into stride-22 padded layout
        const float2* ga = reinterpret_cast<const float2*>(alphas + (size_t)base * 20);
        int npairs = min(TPB1, L - base) * 10;
        for (int j = tid; j < npairs; j += TPB1) {
            int r = j / 10, o = j - r * 10;
            reinterpret_cast<float2*>(sA + r * ASTRIDE)[o] = ga[j];
        }
    }
    __syncthreads();

    if (l >= L) return;

    // ---- rigid_from_3_points ----
    const float* xp = sX + tid * 9;
    float Nx=xp[0], Ny=xp[1], Nz=xp[2];
    float Ax=xp[3], Ay=xp[4], Az=xp[5];
    float Cx=xp[6], Cy=xp[7], Cz=xp[8];

    float v1x=Cx-Ax, v1y=Cy-Ay, v1z=Cz-Az;
    float v2x=Nx-Ax, v2y=Ny-Ay, v2z=Nz-Az;
    float n1 = sqrtf(v1x*v1x + v1y*v1y + v1z*v1z) + 1e-8f;
    float e1x=v1x/n1, e1y=v1y/n1, e1z=v1z/n1;
    float dp = e1x*v2x + e1y*v2y + e1z*v2z;
    float u2x = v2x - dp*e1x, u2y = v2y - dp*e1y, u2z = v2z - dp*e1z;
    float n2 = sqrtf(u2x*u2x + u2y*u2y + u2z*u2z) + 1e-8f;
    float e2x=u2x/n2, e2y=u2y/n2, e2z=u2z/n2;
    float e3x = e1y*e2z - e1z*e2y;
    float e3y = e1z*e2x - e1x*e2z;
    float e3z = e1x*e2y - e1y*e2x;

    float M0[12] = { e1x, e2x, e3x, Ax,
                     e1y, e2y, e3y, Ay,
                     e1z, e2z, e3z, Az };

    int s = seq[l];

    // ---- alphas -> (cos, sin) ----
    float ca[10], sa[10];
    const float* ap = sA + tid * ASTRIDE;
#pragma unroll
    for (int k = 0; k < 10; ++k) {
        float a0 = ap[2*k], a1 = ap[2*k+1];
        float n = sqrtf(a0*a0 + a1*a1) + 1e-6f;
        ca[k] = a0 / n;
        sa[k] = a1 / n;
    }

    float* ofr = outF + (size_t)l * 144;

    // ---- frame 0 ----
    {
        float F[16];
#pragma unroll
        for (int k = 0; k < 12; ++k) F[k] = M0[k];
        F[12]=0.f; F[13]=0.f; F[14]=0.f; F[15]=1.f;
        store16(ofr, F);
    }

    const float* rtbase = RTs + (size_t)s * 112;

    // ---- frames 1..3 ----
#pragma unroll
    for (int k = 0; k < 3; ++k) {
        float Bm[16]; load16(Bm, rtbase + k*16);
        float P[16];
        mul_affine(P, M0, Bm);
        apply_rotX(P, ca[k], sa[k]);
        store16(ofr + (k+1)*16, P);
    }

    // ---- RTF8 ----
    const float* bx = bxyz + (size_t)s * 108;
    float4 b0 = ((const float4*)bx)[0];
    float4 b1 = ((const float4*)bx)[1];
    float4 b2 = ((const float4*)bx)[2];
    float4 b4 = ((const float4*)bx)[4];
    float NCrx = 0.5f*(b2.x+b0.x), NCry = 0.5f*(b2.y+b0.y), NCrz = 0.5f*(b2.z+b0.z);
    float CBAx = b4.x-b1.x, CBAy = b4.y-b1.y, CBAz = b4.z-b1.z;
    float NCAx = NCrx-b1.x, NCAy = NCry-b1.y, NCAz = NCrz-b1.z;
    float a1x = CBAy*NCAz - CBAz*NCAy;
    float a1y = CBAz*NCAx - CBAx*NCAz;
    float a1z = CBAx*NCAy - CBAy*NCAx;
    float a1n = sqrtf(a1x*a1x + a1y*a1y + a1z*a1z) + 1e-8f;
    a1x/=a1n; a1y/=a1n; a1z/=a1n;
    float NCpx = b2.x-b0.x, NCpy = b2.y-b0.y, NCpz = b2.z-b0.z;
    float num = NCpx*NCrx + NCpy*NCry + NCpz*NCrz;
    float den = NCrx*NCrx + NCry*NCry + NCrz*NCrz;
    float tq  = num / den;
    float NCppx = NCpx - tq*NCrx, NCppy = NCpy - tq*NCry, NCppz = NCpz - tq*NCrz;
    float a2x = CBAy*NCppz - CBAz*NCppy;
    float a2y = CBAz*NCppx - CBAx*NCppz;
    float a2z = CBAx*NCppy - CBAy*NCppx;
    float a2n = sqrtf(a2x*a2x + a2y*a2y + a2z*a2z) + 1e-8f;
    a2x/=a2n; a2y/=a2n; a2z/=a2n;

    float C1[9], C2[9], E[9], Fr[9];
    rot_axis3(C1, ca[7], sa[7], a1x, a1y, a1z);
    rot_axis3(C2, ca[8], sa[8], a2x, a2y, a2z);
    mul3_a4(E, M0, C1);
    mul3(Fr, E, C2);

    float M8[12] = { Fr[0],Fr[1],Fr[2],M0[3],
                     Fr[3],Fr[4],Fr[5],M0[7],
                     Fr[6],Fr[7],Fr[8],M0[11] };
    {
        float F[16];
#pragma unroll
        for (int k = 0; k < 12; ++k) F[k] = M8[k];
        F[12]=0.f; F[13]=0.f; F[14]=0.f; F[15]=1.f;
        store16(ofr + 8*16, F);
    }

    // ---- RTF4 ----
    float P[16];
    {
        float Bm[16]; load16(Bm, rtbase + 3*16);
        mul_affine(P, M8, Bm);
        apply_rotX(P, ca[3], sa[3]);
        apply_rotZ(P, ca[9], sa[9]);
        store16(ofr + 4*16, P);
    }

    // ---- RTF5..7 ----
#pragma unroll
    for (int k = 4; k < 7; ++k) {
        float Bm[16]; load16(Bm, rtbase + k*16);
        float Q[16];
        mul_full(Q, P, Bm);
        apply_rotX(Q, ca[k], sa[k]);
        store16(ofr + (k+1)*16, Q);
#pragma unroll
        for (int z = 0; z < 16; ++z) P[z] = Q[z];
    }
}

// ---------- kernel 2: atoms (one thread per output float) ----------

extern "C" __global__ void __launch_bounds__(TPB2)
atoms_kernel(const float* __restrict__ outF,   // (L,9,4,4)
             const float* __restrict__ bxyz,   // (22,27,4)
             const int*   __restrict__ seq,    // (L)
             const int*   __restrict__ bidx,   // (22,27)
             float* __restrict__ outX,         // (L,27,3)
             int total)                        // L*81
{
    int i = blockIdx.x * TPB2 + threadIdx.x;
    if (i >= total) return;

    unsigned ui = (unsigned)i;
    unsigned r = ui / 81u;
    unsigned c = ui - r * 81u;
    unsigned a = c / 3u;
    unsigned d = c - a * 3u;

    int s  = seq[r];
    int ii = s * 27 + (int)a;
    int idx = bidx[ii];

    float4 bv = reinterpret_cast<const float4*>(bxyz)[ii];
    float4 fr = *reinterpret_cast<const float4*>(outF + (size_t)r * 144 + idx * 16 + d * 4);

    float val = fr.x * bv.x;
    val = fmaf(fr.y, bv.y, val);
    val = fmaf(fr.z, bv.z, val);
    val = fmaf(fr.w, bv.w, val);
    outX[i] = val;
}

extern "C" void kernel_launch(void* const* d_in, const int* in_sizes, int n_in,
                              void* d_out, int out_size, void* d_ws, size_t ws_size,
                              hipStream_t stream) {
    const float* xyz    = (const float*)d_in[0];
    const float* alphas = (const float*)d_in[1];
    const float* RTs    = (const float*)d_in[2];
    const float* bxyz   = (const float*)d_in[3];
    const int*   seq    = (const int*)d_in[4];
    const int*   bidx   = (const int*)d_in[5];
    const int L = in_sizes[4];
    float* outF = (float*)d_out;
    float* outX = outF + (size_t)L * 144;

    const int grid1 = (L + TPB1 - 1) / TPB1;
    hipLaunchKernelGGL(frames_kernel, dim3(grid1), dim3(TPB1), 0, stream,
                       xyz, alphas, RTs, bxyz, seq, outF, L);

    const int total = L * 81;
    const int grid2 = (total + TPB2 - 1) / TPB2;
    hipLaunchKernelGGL(atoms_kernel, dim3(grid2), dim3(TPB2), 0, stream,
                       outF, bxyz, seq, bidx, outX, total);
}

// Round 3
// 99.136 us; speedup vs baseline: 1.1687x; 1.1687x over previous
//
#include <hip/hip_runtime.h>

#define TPB 256           // 4 waves: wave w = row w of 64 residues
#define RPB 64            // residues per block
#define ASTRIDE 21        // odd stride -> 2-way LDS alias (free)

// ---------- helpers ----------

__device__ __forceinline__ void load16(float* M, const float* __restrict__ p) {
    const float4* q = reinterpret_cast<const float4*>(p);
    float4 v0 = q[0], v1 = q[1], v2 = q[2], v3 = q[3];
    M[0]=v0.x; M[1]=v0.y; M[2]=v0.z; M[3]=v0.w;
    M[4]=v1.x; M[5]=v1.y; M[6]=v1.z; M[7]=v1.w;
    M[8]=v2.x; M[9]=v2.y; M[10]=v2.z; M[11]=v2.w;
    M[12]=v3.x; M[13]=v3.y; M[14]=v3.z; M[15]=v3.w;
}

// w(1x4) = v(1x4) @ B(4x4 row-major)
__device__ __forceinline__ void vrow_mat(float* __restrict__ w,
                                         const float* __restrict__ v,
                                         const float* __restrict__ B) {
#pragma unroll
    for (int j = 0; j < 4; ++j) {
        float t = v[0] * B[0*4+j];
        t = fmaf(v[1], B[1*4+j], t);
        t = fmaf(v[2], B[2*4+j], t);
        t = fmaf(v[3], B[3*4+j], t);
        w[j] = t;
    }
}

// v = v @ rotX(c,s): cols 1,2 mix
__device__ __forceinline__ void vrotX(float* v, float c, float s) {
    float t1 = v[1], t2 = v[2];
    v[1] = fmaf(t2, s, t1*c);
    v[2] = fmaf(t2, c, -(t1*s));
}

// v = v @ rotZ(c,s): cols 0,1 mix
__device__ __forceinline__ void vrotZ(float* v, float c, float s) {
    float t0 = v[0], t1 = v[1];
    v[0] = fmaf(t1, s, t0*c);
    v[1] = fmaf(t1, c, -(t0*s));
}

__device__ __forceinline__ void rot_axis3(float* R, float ct, float st,
                                          float u0, float u1, float u2) {
    float omc = 1.0f - ct;
    R[0] = ct + u0*u0*omc;       R[1] = u0*u1*omc - u2*st;   R[2] = u0*u2*omc + u1*st;
    R[3] = u0*u1*omc + u2*st;    R[4] = ct + u1*u1*omc;      R[5] = u1*u2*omc - u0*st;
    R[6] = u0*u2*omc - u1*st;    R[7] = u1*u2*omc + u0*st;   R[8] = ct + u2*u2*omc;
}

__device__ __forceinline__ void st4(float* p, float a, float b, float c, float d) {
    *reinterpret_cast<float4*>(p) = make_float4(a, b, c, d);
}

// ---------- fused kernel ----------

extern "C" __global__ void __launch_bounds__(TPB, 4)
caac_kernel(const float* __restrict__ xyz,     // (L,3,3)
            const float* __restrict__ alphas,  // (L,10,2)
            const float* __restrict__ RTs,     // (22,7,4,4)
            const float* __restrict__ bxyz,    // (22,27,4)
            const int*   __restrict__ seq,     // (L)
            const int*   __restrict__ bidx,    // (22,27)
            float* __restrict__ outF,          // (L,9,4,4)
            float* __restrict__ outX,          // (L,27,3)
            int L)
{
    __shared__ float sF[RPB * 144];   // 36.9 KB: frames, mirrors outF layout
    __shared__ int   sSeq[RPB];
    // staging aliases inside sF (consumed before sF is overwritten)
    float* sX = sF;            // RPB*9  floats
    float* sA = sF + RPB * 9;  // RPB*21 floats (padded)

    const int tid     = threadIdx.x;
    const int row     = tid >> 6;      // wave id = frame row (wave-uniform)
    const int r       = tid & 63;      // residue within block
    const int resBase = blockIdx.x * RPB;
    int nres = L - resBase; if (nres > RPB) nres = RPB;

    // ---- stage inputs coalesced ----
    for (int j = tid; j < nres * 9; j += TPB)
        sX[j] = xyz[(size_t)resBase * 9 + j];
    for (int j = tid; j < nres * 20; j += TPB) {
        int rr = j / 20, o = j - rr * 20;
        sA[rr * ASTRIDE + o] = alphas[(size_t)resBase * 20 + j];
    }
    for (int j = tid; j < nres; j += TPB)
        sSeq[j] = seq[resBase + j];
    __syncthreads();

    // ---- pull per-thread inputs to registers (before sF overwrite) ----
    float ca[10], sa[10];
    float v0[4] = {0.f, 0.f, 0.f, 1.f};     // my row of RTF0
    float v8[4] = {0.f, 0.f, 0.f, 1.f};     // my row of RTF8 (pre-chain)
    int s = 0;
    float M0t = 0.f;                        // translation component of my row

    const bool active = (r < nres);
    float e1x=0,e1y=0,e1z=0,e2x=0,e2y=0,e2z=0,e3x=0,e3y=0,e3z=0;

    if (active) {
        s = sSeq[r];
        const float* ap = sA + r * ASTRIDE;
#pragma unroll
        for (int k = 0; k < 10; ++k) {
            float a0 = ap[2*k], a1 = ap[2*k+1];
            float n = sqrtf(a0*a0 + a1*a1) + 1e-6f;
            ca[k] = a0 / n;
            sa[k] = a1 / n;
        }
        if (row < 3) {  // wave-uniform branch: waves 0..2 only
            const float* xp = sX + r * 9;
            float Nx=xp[0], Ny=xp[1], Nz=xp[2];
            float Ax=xp[3], Ay=xp[4], Az=xp[5];
            float Cx=xp[6], Cy=xp[7], Cz=xp[8];
            float v1x=Cx-Ax, v1y=Cy-Ay, v1z=Cz-Az;
            float v2x=Nx-Ax, v2y=Ny-Ay, v2z=Nz-Az;
            float n1 = sqrtf(v1x*v1x + v1y*v1y + v1z*v1z) + 1e-8f;
            e1x=v1x/n1; e1y=v1y/n1; e1z=v1z/n1;
            float dp = e1x*v2x + e1y*v2y + e1z*v2z;
            float u2x = v2x - dp*e1x, u2y = v2y - dp*e1y, u2z = v2z - dp*e1z;
            float n2 = sqrtf(u2x*u2x + u2y*u2y + u2z*u2z) + 1e-8f;
            e2x=u2x/n2; e2y=u2y/n2; e2z=u2z/n2;
            e3x = e1y*e2z - e1z*e2y;
            e3y = e1z*e2x - e1x*e2z;
            e3z = e1x*e2y - e1y*e2x;
            // row `row` of RTF0 = [e1[row], e2[row], e3[row], Ca[row]]
            float Tr = (row == 0) ? Ax : (row == 1) ? Ay : Az;
            v0[0] = (row == 0) ? e1x : (row == 1) ? e1y : e1z;
            v0[1] = (row == 0) ? e2x : (row == 1) ? e2y : e2z;
            v0[2] = (row == 0) ? e3x : (row == 1) ? e3y : e3z;
            v0[3] = Tr;
            M0t = Tr;
        }
    }
    __syncthreads();   // staging region free; sF now the frame buffer

    if (active) {
        float* wf = sF + r * 144;
        const float* rtbase = RTs + (size_t)s * 112;

        // frame 0
        st4(wf + 0*16 + row*4, v0[0], v0[1], v0[2], v0[3]);

        // frames 1..3: v0 @ RTk @ rotX(ak)
#pragma unroll
        for (int k = 0; k < 3; ++k) {
            float Bm[16]; load16(Bm, rtbase + k*16);
            float w[4];
            vrow_mat(w, v0, Bm);
            vrotX(w, ca[k], sa[k]);
            st4(wf + (k+1)*16 + row*4, w[0], w[1], w[2], w[3]);
        }

        // frame 8: rows 0..2: v0[0:3] @ C1 @ C2, translation unchanged
        if (row < 3) {
            const float* bx = bxyz + (size_t)s * 108;
            float4 b0 = ((const float4*)bx)[0];
            float4 b1 = ((const float4*)bx)[1];
            float4 b2 = ((const float4*)bx)[2];
            float4 b4 = ((const float4*)bx)[4];
            float NCrx = 0.5f*(b2.x+b0.x), NCry = 0.5f*(b2.y+b0.y), NCrz = 0.5f*(b2.z+b0.z);
            float CBAx = b4.x-b1.x, CBAy = b4.y-b1.y, CBAz = b4.z-b1.z;
            float NCAx = NCrx-b1.x, NCAy = NCry-b1.y, NCAz = NCrz-b1.z;
            float a1x = CBAy*NCAz - CBAz*NCAy;
            float a1y = CBAz*NCAx - CBAx*NCAz;
            float a1z = CBAx*NCAy - CBAy*NCAx;
            float a1n = sqrtf(a1x*a1x + a1y*a1y + a1z*a1z) + 1e-8f;
            a1x/=a1n; a1y/=a1n; a1z/=a1n;
            float NCpx = b2.x-b0.x, NCpy = b2.y-b0.y, NCpz = b2.z-b0.z;
            float num = NCpx*NCrx + NCpy*NCry + NCpz*NCrz;
            float den = NCrx*NCrx + NCry*NCry + NCrz*NCrz;
            float tq  = num / den;
            float NCppx = NCpx - tq*NCrx, NCppy = NCpy - tq*NCry, NCppz = NCpz - tq*NCrz;
            float a2x = CBAy*NCppz - CBAz*NCppy;
            float a2y = CBAz*NCppx - CBAx*NCppz;
            float a2z = CBAx*NCppy - CBAy*NCppx;
            float a2n = sqrtf(a2x*a2x + a2y*a2y + a2z*a2z) + 1e-8f;
            a2x/=a2n; a2y/=a2n; a2z/=a2n;

            float C1[9], C2[9];
            rot_axis3(C1, ca[7], sa[7], a1x, a1y, a1z);
            rot_axis3(C2, ca[8], sa[8], a2x, a2y, a2z);
            float t0, t1, t2;
            t0 = v0[0]*C1[0]; t0 = fmaf(v0[1], C1[3], t0); t0 = fmaf(v0[2], C1[6], t0);
            t1 = v0[0]*C1[1]; t1 = fmaf(v0[1], C1[4], t1); t1 = fmaf(v0[2], C1[7], t1);
            t2 = v0[0]*C1[2]; t2 = fmaf(v0[1], C1[5], t2); t2 = fmaf(v0[2], C1[8], t2);
            float u0, u1, u2;
            u0 = t0*C2[0]; u0 = fmaf(t1, C2[3], u0); u0 = fmaf(t2, C2[6], u0);
            u1 = t0*C2[1]; u1 = fmaf(t1, C2[4], u1); u1 = fmaf(t2, C2[7], u1);
            u2 = t0*C2[2]; u2 = fmaf(t1, C2[5], u2); u2 = fmaf(t2, C2[8], u2);
            v8[0]=u0; v8[1]=u1; v8[2]=u2; v8[3]=M0t;
        }
        st4(wf + 8*16 + row*4, v8[0], v8[1], v8[2], v8[3]);

        // frame 4: v8 @ RT3 @ rotX(a3) @ rotZ(a9)
        float p[4];
        {
            float Bm[16]; load16(Bm, rtbase + 3*16);
            vrow_mat(p, v8, Bm);
            vrotX(p, ca[3], sa[3]);
            vrotZ(p, ca[9], sa[9]);
            st4(wf + 4*16 + row*4, p[0], p[1], p[2], p[3]);
        }

        // frames 5..7: serial chain
#pragma unroll
        for (int k = 4; k < 7; ++k) {
            float Bm[16]; load16(Bm, rtbase + k*16);
            float q[4];
            vrow_mat(q, p, Bm);
            vrotX(q, ca[k], sa[k]);
            st4(wf + (k+1)*16 + row*4, q[0], q[1], q[2], q[3]);
            p[0]=q[0]; p[1]=q[1]; p[2]=q[2]; p[3]=q[3];
        }
    }
    __syncthreads();

    // ---- coalesced LDS -> outF copy (layouts identical) ----
    {
        const int n4 = nres * 36;   // float4 count
        float4* dst = reinterpret_cast<float4*>(outF + (size_t)resBase * 144);
        const float4* src = reinterpret_cast<const float4*>(sF);
        for (int j = tid; j < n4; j += TPB)
            dst[j] = src[j];
    }

    // ---- atom phase: one element per thread-iteration, coalesced outX ----
    {
        const int total = nres * 81;
        float* ox = outX + (size_t)resBase * 81;
        for (int i = tid; i < total; i += TPB) {
            unsigned ui = (unsigned)i;
            unsigned r2 = ui / 81u;
            unsigned c  = ui - r2 * 81u;
            unsigned a  = c / 3u;
            unsigned d  = c - a * 3u;
            int s2  = sSeq[r2];
            int ii  = s2 * 27 + (int)a;
            int idx = bidx[ii];
            float4 bv = reinterpret_cast<const float4*>(bxyz)[ii];
            float4 fr = *reinterpret_cast<const float4*>(sF + r2*144 + idx*16 + d*4);
            float val = fr.x * bv.x;
            val = fmaf(fr.y, bv.y, val);
            val = fmaf(fr.z, bv.z, val);
            val = fmaf(fr.w, bv.w, val);
            ox[i] = val;
        }
    }
}

extern "C" void kernel_launch(void* const* d_in, const int* in_sizes, int n_in,
                              void* d_out, int out_size, void* d_ws, size_t ws_size,
                              hipStream_t stream) {
    const float* xyz    = (const float*)d_in[0];
    const float* alphas = (const float*)d_in[1];
    const float* RTs    = (const float*)d_in[2];
    const float* bxyz   = (const float*)d_in[3];
    const int*   seq    = (const int*)d_in[4];
    const int*   bidx   = (const int*)d_in[5];
    const int L = in_sizes[4];
    float* outF = (float*)d_out;
    float* outX = outF + (size_t)L * 144;

    const int grid = (L + RPB - 1) / RPB;
    hipLaunchKernelGGL(caac_kernel, dim3(grid), dim3(TPB), 0, stream,
                       xyz, alphas, RTs, bxyz, seq, bidx, outF, outX, L);
}